// Round 1
// baseline (293.694 us; speedup 1.0000x reference)
//
#include <hip/hip_runtime.h>
#include <math.h>

#define Bn 32
#define Cn 256
#define Hn 64
#define Wn 64
#define HWn 4096
#define CRn 16   // C / R

__device__ __forceinline__ float sigmoidf_(float v) { return 1.0f / (1.0f + __expf(-v)); }

// ---------------- Kernel 1: per-(b,c) mean & max over HW ----------------
__global__ __launch_bounds__(256) void k_chanstats(const float* __restrict__ x,
                                                   float* __restrict__ avg,
                                                   float* __restrict__ mx) {
    int bc = blockIdx.x;                      // 0 .. B*C-1
    const float4* xv = (const float4*)(x + (size_t)bc * HWn);
    int t = threadIdx.x;
    float s = 0.0f, m = -INFINITY;
#pragma unroll
    for (int j = 0; j < 4; ++j) {             // 4096 floats = 1024 float4 / 256 thr
        float4 v = xv[t + j * 256];
        s += v.x + v.y + v.z + v.w;
        m = fmaxf(m, fmaxf(fmaxf(v.x, v.y), fmaxf(v.z, v.w)));
    }
    // wave64 shuffle reduce
#pragma unroll
    for (int off = 32; off > 0; off >>= 1) {
        s += __shfl_down(s, off);
        m = fmaxf(m, __shfl_down(m, off));
    }
    __shared__ float ss[4], sm[4];
    int wave = t >> 6, lane = t & 63;
    if (lane == 0) { ss[wave] = s; sm[wave] = m; }
    __syncthreads();
    if (t == 0) {
        s = ss[0] + ss[1] + ss[2] + ss[3];
        m = fmaxf(fmaxf(sm[0], sm[1]), fmaxf(sm[2], sm[3]));
        avg[bc] = s * (1.0f / HWn);
        mx[bc]  = m;
    }
}

// ---------------- Kernel 2: shared MLP + sigmoid -> ch_att ----------------
__global__ __launch_bounds__(256) void k_mlp(const float* __restrict__ avg,
                                             const float* __restrict__ mx,
                                             const float* __restrict__ w1,
                                             const float* __restrict__ w2,
                                             float* __restrict__ ch_att) {
    int b = blockIdx.x;
    int t = threadIdx.x;
    __shared__ float sa[Cn], sx[Cn], h[2 * CRn];
    sa[t] = avg[b * Cn + t];
    sx[t] = mx[b * Cn + t];
    __syncthreads();
    if (t < 2 * CRn) {
        int r = t & (CRn - 1);
        const float* v = (t < CRn) ? sa : sx;
        float acc = 0.0f;
        for (int c = 0; c < Cn; ++c) acc += v[c] * w1[r * Cn + c];
        h[t] = fmaxf(acc, 0.0f);              // relu
    }
    __syncthreads();
    float acc = 0.0f;
#pragma unroll
    for (int r = 0; r < CRn; ++r) acc += (h[r] + h[CRn + r]) * w2[t * CRn + r];
    ch_att[b * Cn + t] = sigmoidf_(acc);
}

// ---------------- Kernel 3: per-(b,hw) mean & max over C of x*ch_att ----------------
__global__ __launch_bounds__(256) void k_spstats(const float* __restrict__ x,
                                                 const float* __restrict__ ch_att,
                                                 float* __restrict__ avg_sp,
                                                 float* __restrict__ max_sp) {
    int p = blockIdx.x * 256 + threadIdx.x;   // b*HW + hw ; 256 | 4096 so b uniform per block
    int b = p >> 12;
    int hw = p & (HWn - 1);
    __shared__ float satt[Cn];
    satt[threadIdx.x] = ch_att[b * Cn + threadIdx.x];
    __syncthreads();
    const float* xb = x + (size_t)b * Cn * HWn + hw;
    float s = 0.0f, m = -INFINITY;
#pragma unroll 4
    for (int c = 0; c < Cn; ++c) {
        float v = xb[(size_t)c * HWn] * satt[c];
        s += v;
        m = fmaxf(m, v);
    }
    avg_sp[p] = s * (1.0f / Cn);
    max_sp[p] = m;
}

// ---------------- Kernel 4: 7x7 SAME conv on [B,2,H,W] + sigmoid -> att ----------------
__global__ __launch_bounds__(256) void k_conv(const float* __restrict__ avg_sp,
                                              const float* __restrict__ max_sp,
                                              const float* __restrict__ w_sp,
                                              float* __restrict__ att) {
    int p = blockIdx.x * 256 + threadIdx.x;   // b*HW + y*W + x
    int b = p >> 12;
    int hw = p & (HWn - 1);
    int y = hw >> 6, xx = hw & 63;
    __shared__ float wk[98];
    if (threadIdx.x < 98) wk[threadIdx.x] = w_sp[threadIdx.x];   // [0][0][ky][kx], then [0][1][ky][kx]
    __syncthreads();
    const float* ab = avg_sp + b * HWn;
    const float* mb = max_sp + b * HWn;
    float acc = 0.0f;
#pragma unroll
    for (int ky = 0; ky < 7; ++ky) {
        int yy = y + ky - 3;
        if (yy < 0 || yy >= Hn) continue;
#pragma unroll
        for (int kx = 0; kx < 7; ++kx) {
            int xc = xx + kx - 3;
            if (xc < 0 || xc >= Wn) continue;
            int q = yy * Wn + xc;
            acc += ab[q] * wk[ky * 7 + kx] + mb[q] * wk[49 + ky * 7 + kx];
        }
    }
    att[p] = sigmoidf_(acc);
}

// ---------------- Kernel 5: out = x * ch_att * att (float4) ----------------
__global__ __launch_bounds__(256) void k_final(const float* __restrict__ x,
                                               const float* __restrict__ ch_att,
                                               const float* __restrict__ att,
                                               float* __restrict__ out) {
    size_t f = (size_t)blockIdx.x * 256 + threadIdx.x;  // float4 index, total B*C*HW/4
    int bc  = (int)(f >> 10);                 // 1024 float4 per (b,c)
    int hw4 = (int)(f & 1023);
    int b = bc >> 8;
    float ca = ch_att[bc];
    float4 a = ((const float4*)(att + (size_t)b * HWn))[hw4];
    float4 v = ((const float4*)x)[f];
    float4 r;
    r.x = v.x * ca * a.x;
    r.y = v.y * ca * a.y;
    r.z = v.z * ca * a.z;
    r.w = v.w * ca * a.w;
    ((float4*)out)[f] = r;
}

extern "C" void kernel_launch(void* const* d_in, const int* in_sizes, int n_in,
                              void* d_out, int out_size, void* d_ws, size_t ws_size,
                              hipStream_t stream) {
    const float* x    = (const float*)d_in[0];   // [32,256,64,64]
    const float* w1   = (const float*)d_in[1];   // [16,256]
    const float* w2   = (const float*)d_in[2];   // [256,16]
    const float* w_sp = (const float*)d_in[3];   // [1,2,7,7]
    float* out = (float*)d_out;

    // workspace layout (floats)
    float* ws = (float*)d_ws;
    float* avg    = ws;                      // B*C      = 8192
    float* mx     = avg + Bn * Cn;           // 8192
    float* ch_att = mx + Bn * Cn;            // 8192
    float* avg_sp = ch_att + Bn * Cn;        // B*HW     = 131072
    float* max_sp = avg_sp + Bn * HWn;       // 131072
    float* att    = max_sp + Bn * HWn;       // 131072

    k_chanstats<<<Bn * Cn, 256, 0, stream>>>(x, avg, mx);
    k_mlp<<<Bn, 256, 0, stream>>>(avg, mx, w1, w2, ch_att);
    k_spstats<<<Bn * HWn / 256, 256, 0, stream>>>(x, ch_att, avg_sp, max_sp);
    k_conv<<<Bn * HWn / 256, 256, 0, stream>>>(avg_sp, max_sp, w_sp, att);
    k_final<<<(size_t)Bn * Cn * HWn / 4 / 256, 256, 0, stream>>>(x, ch_att, att, out);
}

// Round 2
// 285.605 us; speedup vs baseline: 1.0283x; 1.0283x over previous
//
#include <hip/hip_runtime.h>
#include <math.h>

#define Bn 32
#define Cn 256
#define Hn 64
#define Wn 64
#define HWn 4096
#define CRn 16   // C / R

__device__ __forceinline__ float sigmoidf_(float v) { return 1.0f / (1.0f + __expf(-v)); }

// ---------------- Kernel 1: per-(b,c) mean & max over HW ----------------
__global__ __launch_bounds__(256) void k_chanstats(const float* __restrict__ x,
                                                   float* __restrict__ avg,
                                                   float* __restrict__ mx) {
    int bc = blockIdx.x;                      // 0 .. B*C-1
    const float4* xv = (const float4*)(x + (size_t)bc * HWn);
    int t = threadIdx.x;
    float s = 0.0f, m = -INFINITY;
#pragma unroll
    for (int j = 0; j < 4; ++j) {             // 4096 floats = 1024 float4 / 256 thr
        float4 v = xv[t + j * 256];
        s += v.x + v.y + v.z + v.w;
        m = fmaxf(m, fmaxf(fmaxf(v.x, v.y), fmaxf(v.z, v.w)));
    }
    // wave64 shuffle reduce
#pragma unroll
    for (int off = 32; off > 0; off >>= 1) {
        s += __shfl_down(s, off);
        m = fmaxf(m, __shfl_down(m, off));
    }
    __shared__ float ss[4], sm[4];
    int wave = t >> 6, lane = t & 63;
    if (lane == 0) { ss[wave] = s; sm[wave] = m; }
    __syncthreads();
    if (t == 0) {
        s = ss[0] + ss[1] + ss[2] + ss[3];
        m = fmaxf(fmaxf(sm[0], sm[1]), fmaxf(sm[2], sm[3]));
        avg[bc] = s * (1.0f / HWn);
        mx[bc]  = m;
    }
}

// ---------------- Kernel 2: shared MLP + sigmoid -> ch_att ----------------
__global__ __launch_bounds__(256) void k_mlp(const float* __restrict__ avg,
                                             const float* __restrict__ mx,
                                             const float* __restrict__ w1,
                                             const float* __restrict__ w2,
                                             float* __restrict__ ch_att) {
    int b = blockIdx.x;
    int t = threadIdx.x;
    __shared__ float sa[Cn], sx[Cn], h[2 * CRn];
    sa[t] = avg[b * Cn + t];
    sx[t] = mx[b * Cn + t];
    __syncthreads();
    if (t < 2 * CRn) {
        int r = t & (CRn - 1);
        const float* v = (t < CRn) ? sa : sx;
        float acc = 0.0f;
        for (int c = 0; c < Cn; ++c) acc += v[c] * w1[r * Cn + c];
        h[t] = fmaxf(acc, 0.0f);              // relu
    }
    __syncthreads();
    float acc = 0.0f;
#pragma unroll
    for (int r = 0; r < CRn; ++r) acc += (h[r] + h[CRn + r]) * w2[t * CRn + r];
    ch_att[b * Cn + t] = sigmoidf_(acc);
}

// ---------------- Kernel 3: per-(b,hw) mean & max over C of x*ch_att ----------------
// Block = 256 thr = 4 c-groups x 64 hw-float4 lanes. Block covers 256 hw (one b),
// each thread sums/maxes 64 channels with float4 (16B/lane) loads, then LDS-reduce
// across the 4 c-groups. Grid = B * HW/256 = 512.
__global__ __launch_bounds__(256) void k_spstats(const float* __restrict__ x,
                                                 const float* __restrict__ ch_att,
                                                 float* __restrict__ avg_sp,
                                                 float* __restrict__ max_sp) {
    int blk = blockIdx.x;
    int b = blk >> 4;                     // 16 blocks per batch
    int hwbase = (blk & 15) * 256;        // float offset within the b-plane
    int t = threadIdx.x;
    int tg = t >> 6;                      // channel group 0..3
    int lane = t & 63;                    // float4 index within the 256-float tile

    __shared__ float satt[Cn];
    satt[t] = ch_att[b * Cn + t];
    __syncthreads();

    const float* xb = x + (size_t)b * Cn * HWn + hwbase;
    float4 s = {0.f, 0.f, 0.f, 0.f};
    float4 m = {-INFINITY, -INFINITY, -INFINITY, -INFINITY};
#pragma unroll 8
    for (int i = 0; i < 64; ++i) {
        int c = (tg << 6) + i;
        float4 v = ((const float4*)(xb + (size_t)c * HWn))[lane];
        float a = satt[c];
        v.x *= a; v.y *= a; v.z *= a; v.w *= a;
        s.x += v.x; s.y += v.y; s.z += v.z; s.w += v.w;
        m.x = fmaxf(m.x, v.x); m.y = fmaxf(m.y, v.y);
        m.z = fmaxf(m.z, v.z); m.w = fmaxf(m.w, v.w);
    }

    __shared__ float4 rs[4][64];
    __shared__ float4 rm[4][64];
    rs[tg][lane] = s;
    rm[tg][lane] = m;
    __syncthreads();
    if (tg == 0) {
#pragma unroll
        for (int g = 1; g < 4; ++g) {
            float4 os = rs[g][lane], om = rm[g][lane];
            s.x += os.x; s.y += os.y; s.z += os.z; s.w += os.w;
            m.x = fmaxf(m.x, om.x); m.y = fmaxf(m.y, om.y);
            m.z = fmaxf(m.z, om.z); m.w = fmaxf(m.w, om.w);
        }
        const float inv = 1.0f / Cn;
        float4 av = {s.x * inv, s.y * inv, s.z * inv, s.w * inv};
        ((float4*)(avg_sp + b * HWn + hwbase))[lane] = av;
        ((float4*)(max_sp + b * HWn + hwbase))[lane] = m;
    }
}

// ---------------- Kernel 4: 7x7 SAME conv on [B,2,H,W] + sigmoid -> att ----------------
__global__ __launch_bounds__(256) void k_conv(const float* __restrict__ avg_sp,
                                              const float* __restrict__ max_sp,
                                              const float* __restrict__ w_sp,
                                              float* __restrict__ att) {
    int p = blockIdx.x * 256 + threadIdx.x;   // b*HW + y*W + x
    int b = p >> 12;
    int hw = p & (HWn - 1);
    int y = hw >> 6, xx = hw & 63;
    __shared__ float wk[98];
    if (threadIdx.x < 98) wk[threadIdx.x] = w_sp[threadIdx.x];
    __syncthreads();
    const float* ab = avg_sp + b * HWn;
    const float* mb = max_sp + b * HWn;
    float acc = 0.0f;
#pragma unroll
    for (int ky = 0; ky < 7; ++ky) {
        int yy = y + ky - 3;
        if (yy < 0 || yy >= Hn) continue;
#pragma unroll
        for (int kx = 0; kx < 7; ++kx) {
            int xc = xx + kx - 3;
            if (xc < 0 || xc >= Wn) continue;
            int q = yy * Wn + xc;
            acc += ab[q] * wk[ky * 7 + kx] + mb[q] * wk[49 + ky * 7 + kx];
        }
    }
    att[p] = sigmoidf_(acc);
}

// ---------------- Kernel 5: out = x * ch_att * att (float4) ----------------
__global__ __launch_bounds__(256) void k_final(const float* __restrict__ x,
                                               const float* __restrict__ ch_att,
                                               const float* __restrict__ att,
                                               float* __restrict__ out) {
    size_t f = (size_t)blockIdx.x * 256 + threadIdx.x;  // float4 index
    int bc  = (int)(f >> 10);                 // 1024 float4 per (b,c)
    int hw4 = (int)(f & 1023);
    int b = bc >> 8;
    float ca = ch_att[bc];
    float4 a = ((const float4*)(att + (size_t)b * HWn))[hw4];
    float4 v = ((const float4*)x)[f];
    float4 r;
    r.x = v.x * ca * a.x;
    r.y = v.y * ca * a.y;
    r.z = v.z * ca * a.z;
    r.w = v.w * ca * a.w;
    ((float4*)out)[f] = r;
}

extern "C" void kernel_launch(void* const* d_in, const int* in_sizes, int n_in,
                              void* d_out, int out_size, void* d_ws, size_t ws_size,
                              hipStream_t stream) {
    const float* x    = (const float*)d_in[0];   // [32,256,64,64]
    const float* w1   = (const float*)d_in[1];   // [16,256]
    const float* w2   = (const float*)d_in[2];   // [256,16]
    const float* w_sp = (const float*)d_in[3];   // [1,2,7,7]
    float* out = (float*)d_out;

    float* ws = (float*)d_ws;
    float* avg    = ws;                      // B*C
    float* mx     = avg + Bn * Cn;
    float* ch_att = mx + Bn * Cn;
    float* avg_sp = ch_att + Bn * Cn;        // B*HW
    float* max_sp = avg_sp + Bn * HWn;
    float* att    = max_sp + Bn * HWn;

    k_chanstats<<<Bn * Cn, 256, 0, stream>>>(x, avg, mx);
    k_mlp<<<Bn, 256, 0, stream>>>(avg, mx, w1, w2, ch_att);
    k_spstats<<<Bn * HWn / 256, 256, 0, stream>>>(x, ch_att, avg_sp, max_sp);
    k_conv<<<Bn * HWn / 256, 256, 0, stream>>>(avg_sp, max_sp, w_sp, att);
    k_final<<<(size_t)Bn * Cn * HWn / 4 / 256, 256, 0, stream>>>(x, ch_att, att, out);
}